// Round 16
// baseline (66.294 us; speedup 1.0000x reference)
//
#include <hip/hip_runtime.h>
#include <hip/hip_bf16.h>

// Interpolate1D: z = interp(cumsum(softmax(x@W + b)), y); outputs (z[B], x[B,64], logdet[B]+log|slope|)
// B=524288, D=64, R=256.
//
// Round-16 = round-15 (pairing + grid-stride, 64.9us ~ r11's 64.2) + ONE change:
//   __attribute__((amdgpu_waves_per_eu(2,4))) instead of __launch_bounds__(512,2).
//   Across r6/r10/r11/r15 the allocator squeezed every structure to exactly 64 VGPRs
//   (its 8-waves/EU occupancy target), serializing ds_read->MFMA->exp with ONE c in
//   flight — measured time matches the ADDITIVE pipe sum (HBM 33 + LDS 15 + VALU 13
//   + TRANS 3 + MFMA 7 ~ 71us), i.e. no overlap. Real residency never exceeds ~4
//   waves/SIMD in any config, so squeezing to 64 buys nothing. waves_per_eu(2,4)
//   caps the occupancy TARGET at 4 waves/EU -> 128-reg budget the scheduler will
//   spend on software-pipelining the paired chains. (min=2 keeps the allocator from
//   the r8/r9 demand-spill failure; this brackets, not demands.)
// Everything else byte-identical to r15 for a clean A/B.

#define NB 524288
#define NWT (NB / 16)       // 32768 tiles of 16 rows
#define NPAIRS 16384
#define NWAVES 4096         // 512 blocks x 8 waves; 4 pair-iterations each

typedef __attribute__((ext_vector_type(4))) float f32x4;
typedef __attribute__((ext_vector_type(4))) unsigned int u32x4;
typedef __attribute__((ext_vector_type(8))) __bf16 bf16x8;

#define LOG2E 1.4426950408889634f

static __device__ __forceinline__ unsigned short f2b(float f) {
    unsigned u = __builtin_bit_cast(unsigned, f);
    u += 0x7fffu + ((u >> 16) & 1u);          // RNE (W pack only; one-time)
    return (unsigned short)(u >> 16);
}
static __device__ __forceinline__ unsigned pk2t(float a, float b) {
    // truncating bf16x2 pack via byte-permute (r12-verified)
    return __builtin_amdgcn_perm(__builtin_bit_cast(unsigned, b),
                                 __builtin_bit_cast(unsigned, a), 0x07060302u);
}

struct TState {
    bf16x8 a0, a1;      // packed x fragments
    float yv, ldv;
    float m[4], pm[4];  // per-lane masks (statically indexed)
    int s;
    int m0;
};

// stage1: passthrough store + bf16 pack + searchsorted + masks -> compact state
static __device__ __forceinline__ TState stage1(
    int wt, f32x4 v0, f32x4 v1, f32x4 v2, f32x4 v3, float yv, float ldv,
    int colb, int kH, const float* sBP, float* out)
{
    TState st;
    st.m0 = wt << 4; st.yv = yv; st.ldv = ldv;

    float* xo = out + NB + (size_t)(st.m0 + colb) * 64 + (kH << 3);
    *reinterpret_cast<f32x4*>(xo)      = v0;
    *reinterpret_cast<f32x4*>(xo + 4)  = v1;
    *reinterpret_cast<f32x4*>(xo + 32) = v2;
    *reinterpret_cast<f32x4*>(xo + 36) = v3;

    u32x4 pa, pb;
    pa[0] = pk2t(v0[0], v0[1]); pa[1] = pk2t(v0[2], v0[3]);
    pa[2] = pk2t(v1[0], v1[1]); pa[3] = pk2t(v1[2], v1[3]);
    pb[0] = pk2t(v2[0], v2[1]); pb[1] = pk2t(v2[2], v2[3]);
    pb[2] = pk2t(v3[0], v3[1]); pb[3] = pk2t(v3[2], v3[3]);
    st.a0 = __builtin_bit_cast(bf16x8, pa);
    st.a1 = __builtin_bit_cast(bf16x8, pb);

    int s = (int)floorf(yv * 255.0f);
    s = min(254, max(0, s));
    s += (sBP[s + 1] <= yv) ? 1 : 0;
    s = min(s, 254);
    s -= (sBP[s] > yv) ? 1 : 0;
    s = max(s, 0);
    st.s = s;

    const int so  = s & 15;
    const int so1 = (s + 1) & 15;
    #pragma unroll
    for (int j = 0; j < 4; ++j) {
        st.m[j]  = ((kH << 2) + j <= so)  ? 1.f : 0.f;
        st.pm[j] = ((kH << 2) + j == so1) ? 1.f : 0.f;
    }
    return st;
}

// stage2: shared-W fused n-loop for a PAIR of tiles + reduce + final stores
static __device__ __forceinline__ void stage2_pair(
    const TState& A, const TState& B, int lane, int colb, int kH,
    const unsigned short* sW, const float* sBP, const float* sBias, float* out)
{
    const int sbA = A.s >> 4, sbA1 = (A.s + 1) >> 4;
    const int sbB = B.s >> 4, sbB1 = (B.s + 1) >> 4;

    float dA = 0.f, fA = 0.f, pA = 0.f;
    float dB = 0.f, fB = 0.f, pB = 0.f;
    #pragma unroll
    for (int n = 0; n < 16; ++n) {
        bf16x8 w0 = *reinterpret_cast<const bf16x8*>(&sW[(n * 64 + lane) * 8]);
        bf16x8 w1 = *reinterpret_cast<const bf16x8*>(&sW[((16 + n) * 64 + lane) * 8]);
        f32x4 bi = *reinterpret_cast<const f32x4*>(&sBias[(n << 4) + (kH << 2)]);

        f32x4 cA = __builtin_amdgcn_mfma_f32_16x16x32_bf16(w0, A.a0, bi, 0, 0, 0);
        cA = __builtin_amdgcn_mfma_f32_16x16x32_bf16(w1, A.a1, cA, 0, 0, 0);
        f32x4 cB = __builtin_amdgcn_mfma_f32_16x16x32_bf16(w0, B.a0, bi, 0, 0, 0);
        cB = __builtin_amdgcn_mfma_f32_16x16x32_bf16(w1, B.a1, cB, 0, 0, 0);

        {   // tile A epilogue slice
            float e0 = __builtin_amdgcn_exp2f(cA[0]);
            float e1 = __builtin_amdgcn_exp2f(cA[1]);
            float e2 = __builtin_amdgcn_exp2f(cA[2]);
            float e3 = __builtin_amdgcn_exp2f(cA[3]);
            float bs = (e0 + e1) + (e2 + e3);
            dA += bs;
            float t0 = fmaf(e3, A.m[3], fmaf(e2, A.m[2], fmaf(e1, A.m[1], e0 * A.m[0])));
            float tp = fmaf(e3, A.pm[3], fmaf(e2, A.pm[2], fmaf(e1, A.pm[1], e0 * A.pm[0])));
            fA += (n < sbA) ? bs : ((n == sbA) ? t0 : 0.f);
            pA += (n == sbA1) ? tp : 0.f;
        }
        {   // tile B epilogue slice (independent chain)
            float e0 = __builtin_amdgcn_exp2f(cB[0]);
            float e1 = __builtin_amdgcn_exp2f(cB[1]);
            float e2 = __builtin_amdgcn_exp2f(cB[2]);
            float e3 = __builtin_amdgcn_exp2f(cB[3]);
            float bs = (e0 + e1) + (e2 + e3);
            dB += bs;
            float t0 = fmaf(e3, B.m[3], fmaf(e2, B.m[2], fmaf(e1, B.m[1], e0 * B.m[0])));
            float tp = fmaf(e3, B.pm[3], fmaf(e2, B.pm[2], fmaf(e1, B.pm[1], e0 * B.pm[0])));
            fB += (n < sbB) ? bs : ((n == sbB) ? t0 : 0.f);
            pB += (n == sbB1) ? tp : 0.f;
        }
    }

    dA += __shfl_xor(dA, 16, 64); fA += __shfl_xor(fA, 16, 64); pA += __shfl_xor(pA, 16, 64);
    dA += __shfl_xor(dA, 32, 64); fA += __shfl_xor(fA, 32, 64); pA += __shfl_xor(pA, 32, 64);
    dB += __shfl_xor(dB, 16, 64); fB += __shfl_xor(fB, 16, 64); pB += __shfl_xor(pB, 16, 64);
    dB += __shfl_xor(dB, 32, 64); fB += __shfl_xor(fB, 32, 64); pB += __shfl_xor(pB, 32, 64);

    if (kH == 0) {
        {
            float x0 = sBP[A.s], x1 = sBP[A.s + 1];
            float inv = 1.0f / dA;
            float slope = (pA * inv) / (x1 - x0);
            out[A.m0 + colb] = fmaf(slope, A.yv - x0, fA * inv);
            out[(size_t)NB * 65 + A.m0 + colb] = A.ldv + __logf(fabsf(slope));
        }
        {
            float x0 = sBP[B.s], x1 = sBP[B.s + 1];
            float inv = 1.0f / dB;
            float slope = (pB * inv) / (x1 - x0);
            out[B.m0 + colb] = fmaf(slope, B.yv - x0, fB * inv);
            out[(size_t)NB * 65 + B.m0 + colb] = B.ldv + __logf(fabsf(slope));
        }
    }
}

#define LOADT(wt, v0, v1, v2, v3, yv, ldv)                                     \
    {                                                                          \
        const float* xr = x + (size_t)(((wt) << 4) + colb) * 64 + (kH << 3);   \
        v0 = *reinterpret_cast<const f32x4*>(xr);                              \
        v1 = *reinterpret_cast<const f32x4*>(xr + 4);                          \
        v2 = *reinterpret_cast<const f32x4*>(xr + 32);                         \
        v3 = *reinterpret_cast<const f32x4*>(xr + 36);                         \
        yv  = y[((wt) << 4) + colb];                                           \
        ldv = logdet[((wt) << 4) + colb];                                      \
    }

__global__ __launch_bounds__(512)
__attribute__((amdgpu_waves_per_eu(2, 4)))
void interp1d_kernel(
    const float* __restrict__ y, const float* __restrict__ x,
    const float* __restrict__ W, const float* __restrict__ bias,
    const float* __restrict__ logdet, const float* __restrict__ bp,
    float* __restrict__ out)
{
    __shared__ unsigned short sW[2 * 16 * 64 * 8];   // 32KB, [kb][n][lane][i] frag layout
    __shared__ float sBP[256];
    __shared__ float sBias[256];                     // pre-scaled by log2e

    const int t = threadIdx.x;

    // --- once per block: bp, bias*log2e, W*log2e packed into MFMA fragment layout ---
    if (t < 256) {
        sBP[t]   = bp[t];
        sBias[t] = bias[t] * LOG2E;
    }
    {
        const int col = t & 255;
        const int k0  = (t >> 8) << 5;
        const int lane16lo = col & 15;
        const int n = col >> 4;
        for (int kk = 0; kk < 32; ++kk) {
            int k = k0 + kk;
            float wv = W[k * 256 + col] * LOG2E;      // coalesced within each 256-thread half
            int lane16 = ((k >> 3) & 3) * 16 + lane16lo;
            int kb = k >> 5, i = k & 7;
            sW[((kb * 16 + n) * 64 + lane16) * 8 + i] = f2b(wv);
        }
    }
    __syncthreads();

    const int lane = t & 63;
    const int colb = lane & 15;     // this lane's x-row within each tile (C column)
    const int kH   = lane >> 4;     // 0..3
    const int wid  = (blockIdx.x << 3) | (t >> 6);   // 0..4095

    // --- preload first pair (tiles 2*wid, 2*wid+1) ---
    f32x4 A0, A1, A2, A3, B0, B1, B2, B3;
    float yA, lA, yB, lB;
    LOADT(2 * wid,     A0, A1, A2, A3, yA, lA);
    LOADT(2 * wid + 1, B0, B1, B2, B3, yB, lB);

    for (int p = wid; p < NPAIRS; p += NWAVES) {
        const int pn = p + NWAVES;

        // --- stage1 both tiles (consumes the raw x regs: store + pack + search + masks) ---
        TState sA = stage1(2 * p,     A0, A1, A2, A3, yA, lA, colb, kH, sBP, out);
        TState sB = stage1(2 * p + 1, B0, B1, B2, B3, yB, lB, colb, kH, sBP, out);

        // --- prefetch next pair into the now-free x regs; latency hidden by the n-loop ---
        if (pn < NPAIRS) {
            LOADT(2 * pn,     A0, A1, A2, A3, yA, lA);
            LOADT(2 * pn + 1, B0, B1, B2, B3, yB, lB);
        }

        // fence: keep sW ds_reads inside the loop (r3 LICM lesson) + keep prefetch issued
        asm volatile("" ::: "memory");

        // --- shared-W n-loop for the pair + reduce + stores ---
        stage2_pair(sA, sB, lane, colb, kH, sW, sBP, sBias, out);
    }
}

extern "C" void kernel_launch(void* const* d_in, const int* in_sizes, int n_in,
                              void* d_out, int out_size, void* d_ws, size_t ws_size,
                              hipStream_t stream) {
    (void)in_sizes; (void)n_in; (void)out_size; (void)d_ws; (void)ws_size;
    const float* y      = (const float*)d_in[0];
    const float* x      = (const float*)d_in[1];
    const float* W      = (const float*)d_in[2];
    const float* b      = (const float*)d_in[3];
    const float* logdet = (const float*)d_in[4];
    const float* bp     = (const float*)d_in[5];
    float* out = (float*)d_out;
    // 512 blocks x 512 thr = 4096 waves; 16384 pairs -> exactly 4 pair-iters/wave.
    // waves_per_eu(2,4): 128-reg budget actually USED for pipelining (vs the 64-reg
    // squeeze every prior config landed on).
    interp1d_kernel<<<dim3(512), dim3(512), 0, stream>>>(y, x, W, b, logdet, bp, out);
}

// Round 17
// 65.373 us; speedup vs baseline: 1.0141x; 1.0141x over previous
//
#include <hip/hip_runtime.h>
#include <hip/hip_bf16.h>

// Interpolate1D: z = interp(cumsum(softmax(x@W + b)), y); outputs (z[B], x[B,64], logdet[B]+log|slope|)
// B=524288, D=64, R=256.
//
// Round-17 = round-15 (pairing + grid-stride) + LDS PADDED TO 64KB:
//   The allocator sets its register target from LDS-permitted occupancy: 34.8KB ->
//   "4 blocks/CU possible -> 8 waves/SIMD -> 64 regs" and squeezes EVERY structure
//   to 64 regs (r6/r10/r11/r15/r16 all measured exactly 64; r16 proved
//   waves_per_eu(2,4) does NOT override). Real residency is ~3 waves/SIMD, and we
//   launch only 512 blocks = 2/CU anyway — so padding sW to 64KB/block changes
//   NOTHING physically, but flips the allocator target to 4 waves/SIMD = 128 regs,
//   letting it keep both paired chains + pipelined W reads in flight.
//   Single-variable A/B vs r15: if VGPR stays 64 or dur is flat, the 64us plateau
//   is structural and we stop.
// Everything else byte-identical to r15.

#define NB 524288
#define NWT (NB / 16)       // 32768 tiles of 16 rows
#define NPAIRS 16384
#define NWAVES 4096         // 512 blocks x 8 waves; 4 pair-iterations each

typedef __attribute__((ext_vector_type(4))) float f32x4;
typedef __attribute__((ext_vector_type(4))) unsigned int u32x4;
typedef __attribute__((ext_vector_type(8))) __bf16 bf16x8;

#define LOG2E 1.4426950408889634f

static __device__ __forceinline__ unsigned short f2b(float f) {
    unsigned u = __builtin_bit_cast(unsigned, f);
    u += 0x7fffu + ((u >> 16) & 1u);          // RNE (W pack only; one-time)
    return (unsigned short)(u >> 16);
}
static __device__ __forceinline__ unsigned pk2t(float a, float b) {
    // truncating bf16x2 pack via byte-permute (r12-verified)
    return __builtin_amdgcn_perm(__builtin_bit_cast(unsigned, b),
                                 __builtin_bit_cast(unsigned, a), 0x07060302u);
}

struct TState {
    bf16x8 a0, a1;      // packed x fragments
    float yv, ldv;
    float m[4], pm[4];  // per-lane masks (statically indexed)
    int s;
    int m0;
};

// stage1: passthrough store + bf16 pack + searchsorted + masks -> compact state
static __device__ __forceinline__ TState stage1(
    int wt, f32x4 v0, f32x4 v1, f32x4 v2, f32x4 v3, float yv, float ldv,
    int colb, int kH, const float* sBP, float* out)
{
    TState st;
    st.m0 = wt << 4; st.yv = yv; st.ldv = ldv;

    float* xo = out + NB + (size_t)(st.m0 + colb) * 64 + (kH << 3);
    *reinterpret_cast<f32x4*>(xo)      = v0;
    *reinterpret_cast<f32x4*>(xo + 4)  = v1;
    *reinterpret_cast<f32x4*>(xo + 32) = v2;
    *reinterpret_cast<f32x4*>(xo + 36) = v3;

    u32x4 pa, pb;
    pa[0] = pk2t(v0[0], v0[1]); pa[1] = pk2t(v0[2], v0[3]);
    pa[2] = pk2t(v1[0], v1[1]); pa[3] = pk2t(v1[2], v1[3]);
    pb[0] = pk2t(v2[0], v2[1]); pb[1] = pk2t(v2[2], v2[3]);
    pb[2] = pk2t(v3[0], v3[1]); pb[3] = pk2t(v3[2], v3[3]);
    st.a0 = __builtin_bit_cast(bf16x8, pa);
    st.a1 = __builtin_bit_cast(bf16x8, pb);

    int s = (int)floorf(yv * 255.0f);
    s = min(254, max(0, s));
    s += (sBP[s + 1] <= yv) ? 1 : 0;
    s = min(s, 254);
    s -= (sBP[s] > yv) ? 1 : 0;
    s = max(s, 0);
    st.s = s;

    const int so  = s & 15;
    const int so1 = (s + 1) & 15;
    #pragma unroll
    for (int j = 0; j < 4; ++j) {
        st.m[j]  = ((kH << 2) + j <= so)  ? 1.f : 0.f;
        st.pm[j] = ((kH << 2) + j == so1) ? 1.f : 0.f;
    }
    return st;
}

// stage2: shared-W fused n-loop for a PAIR of tiles + reduce + final stores
static __device__ __forceinline__ void stage2_pair(
    const TState& A, const TState& B, int lane, int colb, int kH,
    const unsigned short* sW, const float* sBP, const float* sBias, float* out)
{
    const int sbA = A.s >> 4, sbA1 = (A.s + 1) >> 4;
    const int sbB = B.s >> 4, sbB1 = (B.s + 1) >> 4;

    float dA = 0.f, fA = 0.f, pA = 0.f;
    float dB = 0.f, fB = 0.f, pB = 0.f;
    #pragma unroll
    for (int n = 0; n < 16; ++n) {
        bf16x8 w0 = *reinterpret_cast<const bf16x8*>(&sW[(n * 64 + lane) * 8]);
        bf16x8 w1 = *reinterpret_cast<const bf16x8*>(&sW[((16 + n) * 64 + lane) * 8]);
        f32x4 bi = *reinterpret_cast<const f32x4*>(&sBias[(n << 4) + (kH << 2)]);

        f32x4 cA = __builtin_amdgcn_mfma_f32_16x16x32_bf16(w0, A.a0, bi, 0, 0, 0);
        cA = __builtin_amdgcn_mfma_f32_16x16x32_bf16(w1, A.a1, cA, 0, 0, 0);
        f32x4 cB = __builtin_amdgcn_mfma_f32_16x16x32_bf16(w0, B.a0, bi, 0, 0, 0);
        cB = __builtin_amdgcn_mfma_f32_16x16x32_bf16(w1, B.a1, cB, 0, 0, 0);

        {   // tile A epilogue slice
            float e0 = __builtin_amdgcn_exp2f(cA[0]);
            float e1 = __builtin_amdgcn_exp2f(cA[1]);
            float e2 = __builtin_amdgcn_exp2f(cA[2]);
            float e3 = __builtin_amdgcn_exp2f(cA[3]);
            float bs = (e0 + e1) + (e2 + e3);
            dA += bs;
            float t0 = fmaf(e3, A.m[3], fmaf(e2, A.m[2], fmaf(e1, A.m[1], e0 * A.m[0])));
            float tp = fmaf(e3, A.pm[3], fmaf(e2, A.pm[2], fmaf(e1, A.pm[1], e0 * A.pm[0])));
            fA += (n < sbA) ? bs : ((n == sbA) ? t0 : 0.f);
            pA += (n == sbA1) ? tp : 0.f;
        }
        {   // tile B epilogue slice (independent chain)
            float e0 = __builtin_amdgcn_exp2f(cB[0]);
            float e1 = __builtin_amdgcn_exp2f(cB[1]);
            float e2 = __builtin_amdgcn_exp2f(cB[2]);
            float e3 = __builtin_amdgcn_exp2f(cB[3]);
            float bs = (e0 + e1) + (e2 + e3);
            dB += bs;
            float t0 = fmaf(e3, B.m[3], fmaf(e2, B.m[2], fmaf(e1, B.m[1], e0 * B.m[0])));
            float tp = fmaf(e3, B.pm[3], fmaf(e2, B.pm[2], fmaf(e1, B.pm[1], e0 * B.pm[0])));
            fB += (n < sbB) ? bs : ((n == sbB) ? t0 : 0.f);
            pB += (n == sbB1) ? tp : 0.f;
        }
    }

    dA += __shfl_xor(dA, 16, 64); fA += __shfl_xor(fA, 16, 64); pA += __shfl_xor(pA, 16, 64);
    dA += __shfl_xor(dA, 32, 64); fA += __shfl_xor(fA, 32, 64); pA += __shfl_xor(pA, 32, 64);
    dB += __shfl_xor(dB, 16, 64); fB += __shfl_xor(fB, 16, 64); pB += __shfl_xor(pB, 16, 64);
    dB += __shfl_xor(dB, 32, 64); fB += __shfl_xor(fB, 32, 64); pB += __shfl_xor(pB, 32, 64);

    if (kH == 0) {
        {
            float x0 = sBP[A.s], x1 = sBP[A.s + 1];
            float inv = 1.0f / dA;
            float slope = (pA * inv) / (x1 - x0);
            out[A.m0 + colb] = fmaf(slope, A.yv - x0, fA * inv);
            out[(size_t)NB * 65 + A.m0 + colb] = A.ldv + __logf(fabsf(slope));
        }
        {
            float x0 = sBP[B.s], x1 = sBP[B.s + 1];
            float inv = 1.0f / dB;
            float slope = (pB * inv) / (x1 - x0);
            out[B.m0 + colb] = fmaf(slope, B.yv - x0, fB * inv);
            out[(size_t)NB * 65 + B.m0 + colb] = B.ldv + __logf(fabsf(slope));
        }
    }
}

#define LOADT(wt, v0, v1, v2, v3, yv, ldv)                                     \
    {                                                                          \
        const float* xr = x + (size_t)(((wt) << 4) + colb) * 64 + (kH << 3);   \
        v0 = *reinterpret_cast<const f32x4*>(xr);                              \
        v1 = *reinterpret_cast<const f32x4*>(xr + 4);                          \
        v2 = *reinterpret_cast<const f32x4*>(xr + 32);                         \
        v3 = *reinterpret_cast<const f32x4*>(xr + 36);                         \
        yv  = y[((wt) << 4) + colb];                                           \
        ldv = logdet[((wt) << 4) + colb];                                      \
    }

__global__ __launch_bounds__(512) void interp1d_kernel(
    const float* __restrict__ y, const float* __restrict__ x,
    const float* __restrict__ W, const float* __restrict__ bias,
    const float* __restrict__ logdet, const float* __restrict__ bp,
    float* __restrict__ out)
{
    // sW padded: 32KB used + ~30KB pad -> 64KB total LDS/block. Physically free
    // (we launch 2 blocks/CU either way); flips the allocator's occupancy target
    // from 8 waves/SIMD (64-reg squeeze) to 4 waves/SIMD (128-reg budget).
    __shared__ unsigned short sW[2 * 16 * 64 * 8 + 15360];
    __shared__ float sBP[256];
    __shared__ float sBias[256];                     // pre-scaled by log2e

    const int t = threadIdx.x;

    // --- once per block: bp, bias*log2e, W*log2e packed into MFMA fragment layout ---
    if (t < 256) {
        sBP[t]   = bp[t];
        sBias[t] = bias[t] * LOG2E;
    }
    {
        const int col = t & 255;
        const int k0  = (t >> 8) << 5;
        const int lane16lo = col & 15;
        const int n = col >> 4;
        for (int kk = 0; kk < 32; ++kk) {
            int k = k0 + kk;
            float wv = W[k * 256 + col] * LOG2E;      // coalesced within each 256-thread half
            int lane16 = ((k >> 3) & 3) * 16 + lane16lo;
            int kb = k >> 5, i = k & 7;
            sW[((kb * 16 + n) * 64 + lane16) * 8 + i] = f2b(wv);
        }
    }
    __syncthreads();

    const int lane = t & 63;
    const int colb = lane & 15;     // this lane's x-row within each tile (C column)
    const int kH   = lane >> 4;     // 0..3
    const int wid  = (blockIdx.x << 3) | (t >> 6);   // 0..4095

    // --- preload first pair (tiles 2*wid, 2*wid+1) ---
    f32x4 A0, A1, A2, A3, B0, B1, B2, B3;
    float yA, lA, yB, lB;
    LOADT(2 * wid,     A0, A1, A2, A3, yA, lA);
    LOADT(2 * wid + 1, B0, B1, B2, B3, yB, lB);

    for (int p = wid; p < NPAIRS; p += NWAVES) {
        const int pn = p + NWAVES;

        // --- stage1 both tiles (consumes the raw x regs: store + pack + search + masks) ---
        TState sA = stage1(2 * p,     A0, A1, A2, A3, yA, lA, colb, kH, sBP, out);
        TState sB = stage1(2 * p + 1, B0, B1, B2, B3, yB, lB, colb, kH, sBP, out);

        // --- prefetch next pair into the now-free x regs; latency hidden by the n-loop ---
        if (pn < NPAIRS) {
            LOADT(2 * pn,     A0, A1, A2, A3, yA, lA);
            LOADT(2 * pn + 1, B0, B1, B2, B3, yB, lB);
        }

        // fence: keep sW ds_reads inside the loop (r3 LICM lesson) + keep prefetch issued
        asm volatile("" ::: "memory");

        // --- shared-W n-loop for the pair + reduce + stores ---
        stage2_pair(sA, sB, lane, colb, kH, sW, sBP, sBias, out);
    }
}

extern "C" void kernel_launch(void* const* d_in, const int* in_sizes, int n_in,
                              void* d_out, int out_size, void* d_ws, size_t ws_size,
                              hipStream_t stream) {
    (void)in_sizes; (void)n_in; (void)out_size; (void)d_ws; (void)ws_size;
    const float* y      = (const float*)d_in[0];
    const float* x      = (const float*)d_in[1];
    const float* W      = (const float*)d_in[2];
    const float* b      = (const float*)d_in[3];
    const float* logdet = (const float*)d_in[4];
    const float* bp     = (const float*)d_in[5];
    float* out = (float*)d_out;
    // 512 blocks x 512 thr = 4096 waves; 16384 pairs -> 4 pair-iters/wave.
    // 2 blocks/CU (64KB LDS each) — same physical residency as r15, bigger reg budget.
    interp1d_kernel<<<dim3(512), dim3(512), 0, stream>>>(y, x, W, b, logdet, bp, out);
}

// Round 18
// 59.535 us; speedup vs baseline: 1.1135x; 1.0981x over previous
//
#include <hip/hip_runtime.h>
#include <hip/hip_bf16.h>

// Interpolate1D: z = interp(cumsum(softmax(x@W + b)), y); outputs (z[B], x[B,64], logdet[B]+log|slope|)
// B=524288, D=64, R=256.
//
// Round-18 = round-11 (best: 64.2us) + ONE change: NON-TEMPORAL passthrough stores.
//   Counter anomaly: FETCH_SIZE = 68MB = exactly half of x per dispatch. Mechanism:
//   the 134MB passthrough write stream ALLOCATES in the 256MB Infinity Cache as it
//   streams out; writes + x = 268MB > 256MB L3 -> the write stream continuously
//   evicts x -> each replay re-fetches half of x from HBM. The passthrough output is
//   never re-read by the kernel: pure streaming output. __builtin_nontemporal_store
//   (MUBUF nt flag) keeps it from displacing x -> x stays L3-resident, FETCH -> ~0.
//   Prediction: FETCH 68 -> <25MB; dur 64 -> 52-58 if the re-fetch cost time.
//   If FETCH drops but dur is flat: latency-bound confirmed, plateau declared.
// Everything else byte-identical to r11 (fused n-loop, 512-thr blocks, swapped MFMA
// operands, register prefetch, LICM fence, log2e pre-scale + exp2, float-mask prefix
// sums, branchless searchsorted, truncating bf16 x-pack).

#define NB 524288
#define NWT (NB / 16)   // 32768 wave-tiles of 16 rows

typedef __attribute__((ext_vector_type(4))) float f32x4;
typedef __attribute__((ext_vector_type(4))) unsigned int u32x4;
typedef __attribute__((ext_vector_type(8))) __bf16 bf16x8;

#define LOG2E 1.4426950408889634f

static __device__ __forceinline__ unsigned short f2b(float f) {
    unsigned u = __builtin_bit_cast(unsigned, f);
    u += 0x7fffu + ((u >> 16) & 1u);          // RNE (W pack only; one-time)
    return (unsigned short)(u >> 16);
}
static __device__ __forceinline__ unsigned pk2t(float a, float b) {
    // truncating bf16x2 pack: hi16(a) | hi16(b)
    return (__builtin_bit_cast(unsigned, a) >> 16) | (__builtin_bit_cast(unsigned, b) & 0xffff0000u);
}

__global__ __launch_bounds__(512, 4) void interp1d_kernel(
    const float* __restrict__ y, const float* __restrict__ x,
    const float* __restrict__ W, const float* __restrict__ bias,
    const float* __restrict__ logdet, const float* __restrict__ bp,
    float* __restrict__ out)
{
    __shared__ unsigned short sW[2 * 16 * 64 * 8];   // 32KB, [kb][n][lane][i] frag layout
    __shared__ float sBP[256];
    __shared__ float sBias[256];                     // pre-scaled by log2e

    const int t = threadIdx.x;

    // --- once per block: bp, bias*log2e, W*log2e packed into MFMA fragment layout ---
    if (t < 256) {
        sBP[t]   = bp[t];
        sBias[t] = bias[t] * LOG2E;
    }
    {
        const int col = t & 255;
        const int k0  = (t >> 8) << 5;
        const int lane16lo = col & 15;
        const int n = col >> 4;
        for (int kk = 0; kk < 32; ++kk) {
            int k = k0 + kk;
            float wv = W[k * 256 + col] * LOG2E;      // coalesced within each 256-thread half
            int lane16 = ((k >> 3) & 3) * 16 + lane16lo;
            int kb = k >> 5, i = k & 7;
            sW[((kb * 16 + n) * 64 + lane16) * 8 + i] = f2b(wv);
        }
    }
    __syncthreads();

    const int lane = t & 63;
    const int colb = lane & 15;     // this lane's x-row within the tile (C column)
    const int kH   = lane >> 4;     // 0..3: k-half for frags; C row group (cols kH*4+j)
    const int nw   = gridDim.x << 3;            // 8 waves per block

    int wt = (blockIdx.x << 3) | (t >> 6);

    // --- preload first tile ---
    f32x4 v0 = {}, v1 = {}, v2 = {}, v3 = {};
    float yv = 0.f, ldv = 0.f;
    if (wt < NWT) {
        const float* xr = x + (size_t)((wt << 4) + colb) * 64 + (kH << 3);
        v0 = *reinterpret_cast<const f32x4*>(xr);
        v1 = *reinterpret_cast<const f32x4*>(xr + 4);
        v2 = *reinterpret_cast<const f32x4*>(xr + 32);
        v3 = *reinterpret_cast<const f32x4*>(xr + 36);
        yv  = y[(wt << 4) + colb];
        ldv = logdet[(wt << 4) + colb];
    }

    for (; wt < NWT; wt += nw) {
        const int m0 = wt << 4;
        const int wtn = wt + nw;

        // --- prefetch next tile (latency hidden under this tile's compute) ---
        f32x4 n0 = {}, n1 = {}, n2 = {}, n3 = {};
        float yn = 0.f, ldn = 0.f;
        if (wtn < NWT) {
            const float* xr = x + (size_t)((wtn << 4) + colb) * 64 + (kH << 3);
            n0 = *reinterpret_cast<const f32x4*>(xr);
            n1 = *reinterpret_cast<const f32x4*>(xr + 4);
            n2 = *reinterpret_cast<const f32x4*>(xr + 32);
            n3 = *reinterpret_cast<const f32x4*>(xr + 36);
            yn  = y[(wtn << 4) + colb];
            ldn = logdet[(wtn << 4) + colb];
        }

        // compiler fence: stop LICM from hoisting sW ds_reads out of the tile loop (r3 lesson)
        asm volatile("" ::: "memory");

        // --- passthrough x store: NON-TEMPORAL (never re-read; don't evict x from L2/L3) ---
        float* xo = out + NB + (size_t)(m0 + colb) * 64 + (kH << 3);
        __builtin_nontemporal_store(v0, reinterpret_cast<f32x4*>(xo));
        __builtin_nontemporal_store(v1, reinterpret_cast<f32x4*>(xo + 4));
        __builtin_nontemporal_store(v2, reinterpret_cast<f32x4*>(xo + 32));
        __builtin_nontemporal_store(v3, reinterpret_cast<f32x4*>(xo + 36));

        // --- pack x into B-fragment (col = x-row = lane&15, k = kH*8+i) ---
        u32x4 pa, pb;
        pa[0] = pk2t(v0[0], v0[1]); pa[1] = pk2t(v0[2], v0[3]);
        pa[2] = pk2t(v1[0], v1[1]); pa[3] = pk2t(v1[2], v1[3]);
        pb[0] = pk2t(v2[0], v2[1]); pb[1] = pk2t(v2[2], v2[3]);
        pb[2] = pk2t(v3[0], v3[1]); pb[3] = pk2t(v3[2], v3[3]);
        bf16x8 a0 = __builtin_bit_cast(bf16x8, pa);
        bf16x8 a1 = __builtin_bit_cast(bf16x8, pb);

        // --- searchsorted (branchless: bp ~ linspace so guess is off by <= 1) ---
        int s = (int)floorf(yv * 255.0f);
        s = min(254, max(0, s));
        s += (sBP[s + 1] <= yv) ? 1 : 0;   // bp[255]=1.0 > yv, can't reach 255
        s = min(s, 254);
        s -= (sBP[s] > yv) ? 1 : 0;
        s = max(s, 0);

        // --- per-lane float masks for the partial blocks ---
        const int sb  = s >> 4,  so  = s & 15;            // block/offset of s
        const int sb1 = (s + 1) >> 4, so1 = (s + 1) & 15; // block/offset of s+1
        float m[4], pm[4];
        #pragma unroll
        for (int j = 0; j < 4; ++j) {
            m[j]  = ((kH << 2) + j <= so)  ? 1.f : 0.f;
            pm[j] = ((kH << 2) + j == so1) ? 1.f : 0.f;
        }

        // --- FUSED n-loop: MFMA (transient c) -> exp2 -> masked sums ---
        float denom = 0.f, f0s = 0.f, p1 = 0.f;
        #pragma unroll
        for (int n = 0; n < 16; ++n) {
            bf16x8 w0 = *reinterpret_cast<const bf16x8*>(&sW[(n * 64 + lane) * 8]);
            bf16x8 w1 = *reinterpret_cast<const bf16x8*>(&sW[((16 + n) * 64 + lane) * 8]);
            f32x4 c = *reinterpret_cast<const f32x4*>(&sBias[(n << 4) + (kH << 2)]);
            c = __builtin_amdgcn_mfma_f32_16x16x32_bf16(w0, a0, c, 0, 0, 0);
            c = __builtin_amdgcn_mfma_f32_16x16x32_bf16(w1, a1, c, 0, 0, 0);
            float e0 = __builtin_amdgcn_exp2f(c[0]);
            float e1 = __builtin_amdgcn_exp2f(c[1]);
            float e2 = __builtin_amdgcn_exp2f(c[2]);
            float e3 = __builtin_amdgcn_exp2f(c[3]);
            float bs = (e0 + e1) + (e2 + e3);
            denom += bs;
            float t0 = fmaf(e3, m[3], fmaf(e2, m[2], fmaf(e1, m[1], e0 * m[0])));
            float tp = fmaf(e3, pm[3], fmaf(e2, pm[2], fmaf(e1, pm[1], e0 * pm[0])));
            f0s += (n < sb) ? bs : ((n == sb) ? t0 : 0.f);
            p1  += (n == sb1) ? tp : 0.f;
        }

        // --- reduce over the 4 kH lanes sharing this x-row ---
        denom += __shfl_xor(denom, 16, 64);
        f0s   += __shfl_xor(f0s,   16, 64);
        p1    += __shfl_xor(p1,    16, 64);
        denom += __shfl_xor(denom, 32, 64);
        f0s   += __shfl_xor(f0s,   32, 64);
        p1    += __shfl_xor(p1,    32, 64);

        if (kH == 0) {   // lanes 0..15 store rows m0..m0+15: contiguous 64B
            float x0 = sBP[s], x1 = sBP[s + 1];
            float inv = 1.0f / denom;
            float f0 = f0s * inv;
            float slope = (p1 * inv) / (x1 - x0);
            out[m0 + colb] = fmaf(slope, yv - x0, f0);
            out[(size_t)NB * 65 + m0 + colb] = ldv + __logf(fabsf(slope));
        }

        // --- rotate prefetched tile in ---
        if (wtn < NWT) {
            v0 = n0; v1 = n1; v2 = n2; v3 = n3;
            yv = yn; ldv = ldn;
        }
    }
}

extern "C" void kernel_launch(void* const* d_in, const int* in_sizes, int n_in,
                              void* d_out, int out_size, void* d_ws, size_t ws_size,
                              hipStream_t stream) {
    (void)in_sizes; (void)n_in; (void)out_size; (void)d_ws; (void)ws_size;
    const float* y      = (const float*)d_in[0];
    const float* x      = (const float*)d_in[1];
    const float* W      = (const float*)d_in[2];
    const float* b      = (const float*)d_in[3];
    const float* logdet = (const float*)d_in[4];
    const float* bp     = (const float*)d_in[5];
    float* out = (float*)d_out;
    // r11 config: 512-thr blocks (8 waves share one 32KB sW), 1024 blocks, 4 tiles/wave.
    interp1d_kernel<<<dim3(1024), dim3(512), 0, stream>>>(y, x, W, b, logdet, bp, out);
}